// Round 1
// baseline (218.655 us; speedup 1.0000x reference)
//
#include <hip/hip_runtime.h>

// RoIAlign: features (2,256,200,304) fp32 NCHW, rois (512,5) fp32,
// out (512,256,7,7) fp32. OUT=7x7, sampling ratio G=2, scale 0.25.
//
// Round 8: transpose tile widened 64x64 -> 64x128 pixels. Phase-1 global
// reads are now 512-B contiguous per channel row per wave instruction
// (was 4x256B) -- doubles HBM burst length on the 243-KB-strided channel
// walk, which round-7 counters suggested was the remaining sub-peak
// stream. Phase-2 repacked to 8-channel groups / uint4 stores (still
// full-128B-line NHWC writes). Row stride 129 (odd) keeps LDS phase-2
// reads at 2 lanes/bank (free); phase-1 scalar writes are 4-way (~5us
// aggregate, hidden under HBM). Gather = round-5 structure, s_off
// premultiplied to byte offsets.

#define OUT_H 7
#define OUT_W 7
constexpr float SPATIAL_SCALE = 0.25f;
constexpr int CN = 256;   // channels
constexpr int FH = 200;
constexpr int FW = 304;
constexpr int N_IMG = 2;
constexpr int N_ROIS = 512;
constexpr int PIX = FH * FW;               // 60800 = 475 * 128
constexpr size_t PLANE = (size_t)PIX;
constexpr size_t NHWC_ELEMS = (size_t)N_IMG * PLANE * CN;
constexpr size_t NHWC_BF16_BYTES = NHWC_ELEMS * sizeof(unsigned short);

constexpr int CT = 64;    // channel tile
constexpr int PT = 128;   // pixel tile (60800 % 128 == 0)

__device__ __forceinline__ unsigned short f2bf_rne(float f) {
    unsigned int u = __float_as_uint(f);
    unsigned int r = (u + 0x7FFFu + ((u >> 16) & 1u)) >> 16;  // RNE
    return (unsigned short)r;
}

// ---------------- tiled transpose NCHW fp32 -> NHWC bf16 ----------------
// grid (PIX/PT = 475, N_IMG*CN/CT = 8), 256 threads.
// Phase 1: thread (q = t&31, r = t>>5) loads float4 of channel c = r + 8i
//   at pixel offset 4q. Per wave instruction (fixed i): lanes 0-31 cover
//   channel r=0's full 128-px row = 512 B contiguous, lanes 32-63 the
//   next channel -> 2 x 512-B bursts per instruction.
// Phase 2: thread (cq = t&7, p0 = t>>3) reads tile[8cq+m][p], m=0..7,
//   packs 8 channels -> uint4, stores 16 B at pixel p = p0 + 32*i2.
//   Per wave instruction: 8 pixels x 128-B full-line NHWC chunks.
//   Bank math (stride 129 ≡ 1 mod 32): read bank = (8cq+m+p0) & 31,
//   (cq,p0) covers 0..63 once -> 2 lanes/bank -> free.
__global__ __launch_bounds__(256) void nchw_to_nhwc_bf16_tiled(
    const float* __restrict__ in, unsigned short* __restrict__ ws)
{
    const int pbase = blockIdx.x * PT;
    const int nc = blockIdx.y;           // 0..7
    const int n = nc >> 2;
    const int cbase = (nc & 3) * CT;

    __shared__ float tile[CT][PT + 1];   // 64 x 129 fp32 = 33,024 B

    {
        const int q = threadIdx.x & 31;  // float4 slot within pixel row
        const int r = threadIdx.x >> 5;  // 0..7
        const float* src = in + ((size_t)n * CN + cbase) * PLANE + pbase + 4 * q;
#pragma unroll
        for (int i = 0; i < 8; ++i) {
            const int c = r + 8 * i;
            const float4 v = *(const float4*)(src + (size_t)c * PLANE);
            tile[c][4 * q + 0] = v.x;
            tile[c][4 * q + 1] = v.y;
            tile[c][4 * q + 2] = v.z;
            tile[c][4 * q + 3] = v.w;
        }
    }
    __syncthreads();
    {
        const int cq = threadIdx.x & 7;  // channel octet: channels 8cq..8cq+7
        const int p0 = threadIdx.x >> 3; // 0..31
        unsigned short* dstbase =
            ws + ((size_t)n * PLANE + pbase) * CN + cbase + 8 * cq;
#pragma unroll
        for (int i2 = 0; i2 < 4; ++i2) {
            const int p = p0 + 32 * i2;
            uint4 pk;
            pk.x = (unsigned int)f2bf_rne(tile[8 * cq + 0][p]) |
                   ((unsigned int)f2bf_rne(tile[8 * cq + 1][p]) << 16);
            pk.y = (unsigned int)f2bf_rne(tile[8 * cq + 2][p]) |
                   ((unsigned int)f2bf_rne(tile[8 * cq + 3][p]) << 16);
            pk.z = (unsigned int)f2bf_rne(tile[8 * cq + 4][p]) |
                   ((unsigned int)f2bf_rne(tile[8 * cq + 5][p]) << 16);
            pk.w = (unsigned int)f2bf_rne(tile[8 * cq + 6][p]) |
                   ((unsigned int)f2bf_rne(tile[8 * cq + 7][p]) << 16);
            *(uint4*)(dstbase + (size_t)p * CN) = pk;
        }
    }
}

// ---------------- gather on NHWC bf16: (roi, ph) blocks, XCD-swizzled ----
// 1-D grid of 3584; decode so all 7 ph of a roi share (id % 8) => same XCD.
__global__ __launch_bounds__(128) void roi_align_nhwc_bf16(
    const unsigned short* __restrict__ ws,
    const float* __restrict__ rois,
    float* __restrict__ out)
{
    const int b = blockIdx.x;
    const int x = b & 7;                 // XCD residue
    const int s_id = b >> 3;             // 0..447
    const int r  = (s_id / 7) * 8 + x;   // roi
    const int ph = s_id % 7;             // output row
    const int t  = threadIdx.x;          // channel pair: 2t, 2t+1

    __shared__ float s_roi[5];
    __shared__ int   s_off[28][4];       // BYTE offsets into NHWC bf16 plane
    __shared__ float s_w[28][4];
    __shared__ int   s_b;

    if (t < 5) s_roi[t] = rois[r * 5 + t];
    __syncthreads();

    if (t < 28) {
        const int s  = t;
        const int gy = s / 14;
        const int ix = s % 14;
        const float x1 = s_roi[1] * SPATIAL_SCALE - 0.5f;
        const float y1 = s_roi[2] * SPATIAL_SCALE - 0.5f;
        const float x2 = s_roi[3] * SPATIAL_SCALE - 0.5f;
        const float y2 = s_roi[4] * SPATIAL_SCALE - 0.5f;
        const float bin_w = (x2 - x1) / OUT_W;
        const float bin_h = (y2 - y1) / OUT_H;
        const float y = y1 + ph * bin_h + (gy + 0.5f) * bin_h * 0.5f;
        const float xf = x1 + (ix >> 1) * bin_w + ((ix & 1) + 0.5f) * bin_w * 0.5f;
        const float validf =
            (y > -1.0f && y < (float)FH && xf > -1.0f && xf < (float)FW) ? 1.0f : 0.0f;
        const float yc = fminf(fmaxf(y, 0.0f), (float)(FH - 1));
        const float xc = fminf(fmaxf(xf, 0.0f), (float)(FW - 1));
        const int y0 = (int)floorf(yc);
        const int x0 = (int)floorf(xc);
        const int y1i = min(y0 + 1, FH - 1);
        const int x1i = min(x0 + 1, FW - 1);
        const float ly = yc - (float)y0;
        const float lx = xc - (float)x0;
        const float hy = 1.0f - ly;
        const float hx = 1.0f - lx;
        s_off[s][0] = ((y0  * FW + x0 ) * CN) * 2;
        s_off[s][1] = ((y0  * FW + x1i) * CN) * 2;
        s_off[s][2] = ((y1i * FW + x0 ) * CN) * 2;
        s_off[s][3] = ((y1i * FW + x1i) * CN) * 2;
        s_w[s][0] = hy * hx * validf;
        s_w[s][1] = hy * lx * validf;
        s_w[s][2] = ly * hx * validf;
        s_w[s][3] = ly * lx * validf;
    }
    if (t == 0) s_b = (int)s_roi[0];
    __syncthreads();

    const char* base =
        (const char*)(ws + (size_t)s_b * (PLANE * CN) + 2 * t);

    float acc0[OUT_W] = {0.f, 0.f, 0.f, 0.f, 0.f, 0.f, 0.f};
    float acc1[OUT_W] = {0.f, 0.f, 0.f, 0.f, 0.f, 0.f, 0.f};
#pragma unroll
    for (int s = 0; s < 28; ++s) {
        const int pw = (s % 14) >> 1;
#pragma unroll
        for (int k = 0; k < 4; ++k) {
            const unsigned int u = *(const unsigned int*)(base + s_off[s][k]);
            const float f0 = __uint_as_float(u << 16);
            const float f1 = __uint_as_float(u & 0xFFFF0000u);
            const float w = s_w[s][k];
            acc0[pw] = fmaf(w, f0, acc0[pw]);
            acc1[pw] = fmaf(w, f1, acc1[pw]);
        }
    }

    const size_t outbase = ((size_t)r * CN + 2 * t) * (OUT_H * OUT_W) + (size_t)ph * OUT_W;
#pragma unroll
    for (int pw = 0; pw < OUT_W; ++pw) {
        out[outbase + pw] = acc0[pw] * 0.25f;
        out[outbase + (OUT_H * OUT_W) + pw] = acc1[pw] * 0.25f;
    }
}

// ---------------- fallback: NCHW gather (round-1 kernel) ----------------
__global__ __launch_bounds__(256) void roi_align_nchw(
    const float* __restrict__ feat,
    const float* __restrict__ rois,
    float* __restrict__ out)
{
    const int r  = blockIdx.x;
    const int ph = blockIdx.y;
    const int c  = threadIdx.x;

    __shared__ float s_roi[5];
    __shared__ int   s_off[28][4];
    __shared__ float s_w[28][4];
    __shared__ int   s_b;

    if (threadIdx.x < 5) s_roi[threadIdx.x] = rois[r * 5 + threadIdx.x];
    __syncthreads();

    if (threadIdx.x < 28) {
        const int s  = threadIdx.x;
        const int gy = s / 14;
        const int ix = s % 14;
        const float x1 = s_roi[1] * SPATIAL_SCALE - 0.5f;
        const float y1 = s_roi[2] * SPATIAL_SCALE - 0.5f;
        const float x2 = s_roi[3] * SPATIAL_SCALE - 0.5f;
        const float y2 = s_roi[4] * SPATIAL_SCALE - 0.5f;
        const float bin_w = (x2 - x1) / OUT_W;
        const float bin_h = (y2 - y1) / OUT_H;
        const float y = y1 + ph * bin_h + (gy + 0.5f) * bin_h * 0.5f;
        const float xf = x1 + (ix >> 1) * bin_w + ((ix & 1) + 0.5f) * bin_w * 0.5f;
        const float validf =
            (y > -1.0f && y < (float)FH && xf > -1.0f && xf < (float)FW) ? 1.0f : 0.0f;
        const float yc = fminf(fmaxf(y, 0.0f), (float)(FH - 1));
        const float xc = fminf(fmaxf(xf, 0.0f), (float)(FW - 1));
        const int y0 = (int)floorf(yc);
        const int x0 = (int)floorf(xc);
        const int y1i = min(y0 + 1, FH - 1);
        const int x1i = min(x0 + 1, FW - 1);
        const float ly = yc - (float)y0;
        const float lx = xc - (float)x0;
        const float hy = 1.0f - ly;
        const float hx = 1.0f - lx;
        s_off[s][0] = y0  * FW + x0;
        s_off[s][1] = y0  * FW + x1i;
        s_off[s][2] = y1i * FW + x0;
        s_off[s][3] = y1i * FW + x1i;
        s_w[s][0] = hy * hx * validf;
        s_w[s][1] = hy * lx * validf;
        s_w[s][2] = ly * hx * validf;
        s_w[s][3] = ly * lx * validf;
    }
    if (threadIdx.x == 0) s_b = (int)s_roi[0];
    __syncthreads();

    const float* base = feat + ((size_t)s_b * CN + c) * PLANE;

    float acc[OUT_W] = {0.f, 0.f, 0.f, 0.f, 0.f, 0.f, 0.f};
#pragma unroll
    for (int s = 0; s < 28; ++s) {
        const float v0 = base[s_off[s][0]];
        const float v1 = base[s_off[s][1]];
        const float v2 = base[s_off[s][2]];
        const float v3 = base[s_off[s][3]];
        acc[(s % 14) >> 1] += s_w[s][0] * v0 + s_w[s][1] * v1 +
                              s_w[s][2] * v2 + s_w[s][3] * v3;
    }

    const size_t outbase = ((size_t)r * CN + c) * (OUT_H * OUT_W) + (size_t)ph * OUT_W;
#pragma unroll
    for (int pw = 0; pw < OUT_W; ++pw) {
        out[outbase + pw] = acc[pw] * 0.25f;
    }
}

extern "C" void kernel_launch(void* const* d_in, const int* in_sizes, int n_in,
                              void* d_out, int out_size, void* d_ws, size_t ws_size,
                              hipStream_t stream) {
    const float* feat = (const float*)d_in[0];
    const float* rois = (const float*)d_in[1];
    float* out = (float*)d_out;

    if (ws_size >= NHWC_BF16_BYTES) {
        unsigned short* ws = (unsigned short*)d_ws;
        dim3 tgrid(PIX / PT, (N_IMG * CN) / CT, 1);  // 475 x 8 = 3800 blocks
        nchw_to_nhwc_bf16_tiled<<<tgrid, dim3(256, 1, 1), 0, stream>>>(feat, ws);
        roi_align_nhwc_bf16<<<dim3(N_ROIS * OUT_H, 1, 1), dim3(128, 1, 1), 0, stream>>>(
            ws, rois, out);
    } else {
        dim3 grid(N_ROIS, OUT_H, 1);
        roi_align_nchw<<<grid, dim3(256, 1, 1), 0, stream>>>(feat, rois, out);
    }
}